// Round 1
// 158.092 us; speedup vs baseline: 1.0512x; 1.0512x over previous
//
#include <hip/hip_runtime.h>
#include <math.h>

#define BATCH 4
#define CH    256
#define NPIX  4096
#define DQK   32

typedef short          s16;
typedef unsigned int   uint_t;
typedef __attribute__((ext_vector_type(8))) short short8;   // 8 bf16 (4 VGPRs)
typedef __attribute__((ext_vector_type(4))) float floatx4;  // MFMA C/D 16x16
typedef __attribute__((ext_vector_type(16))) float floatx16; // MFMA C/D 32x32

__device__ __forceinline__ s16 f2bf(float f) {
  union { float f; uint_t u; } v; v.f = f;
  return (s16)((v.u + 0x8000u) >> 16);
}
__device__ __forceinline__ uint_t pk2(float a, float b) {
  union { float f; uint_t u; } x, y; x.f = a; y.f = b;
  return (((y.u + 0x8000u) >> 16) << 16) | ((x.u + 0x8000u) >> 16);
}

// ============ prepack: W (fp32, rows Q32|K32|V256) -> bf16 [320][256] ======
__global__ __launch_bounds__(256) void prepack(
    const float* __restrict__ Wq, const float* __restrict__ bq,
    const float* __restrict__ Wk, const float* __restrict__ bk,
    const float* __restrict__ Wv, const float* __restrict__ bv,
    s16* __restrict__ Wbf, float* __restrict__ Bsw)
{
  const int gid = blockIdx.x * 256 + threadIdx.x;   // grid 80
  const int e0  = gid * 4;
  const int row = e0 >> 8, col = e0 & 255;
  const float* src = (row < 32) ? Wq + (size_t)row * 256
                   : (row < 64) ? Wk + (size_t)(row - 32) * 256
                                : Wv + (size_t)(row - 64) * 256;
  float4 f = *(const float4*)(src + col);
  uint2 o; o.x = pk2(f.x, f.y); o.y = pk2(f.z, f.w);
  *(uint2*)(Wbf + e0) = o;
  if (gid < 320)
    Bsw[gid] = (gid < 32) ? bq[gid] : (gid < 64) ? bk[gid - 32] : bv[gid - 64];
}

// ============ proj: [Q;K;V] = W'·X, 32-px tiles, grid 512 (2 blocks/CU) ====
// Out: Q,K bf16 [b][n][32] ; V bf16 [b][c][n].
__global__ __launch_bounds__(256, 2) void proj_mfma(
    const float* __restrict__ x, const s16* __restrict__ Wbf,
    const float* __restrict__ Bsw,
    s16* __restrict__ Qw, s16* __restrict__ Kw, s16* __restrict__ Vw)
{
  const int b  = blockIdx.x >> 7;
  const int n0 = (blockIdx.x & 127) << 5;
  const int t  = threadIdx.x;

  __shared__ s16 Xs[32][264];   // [n][k] bf16
  __shared__ s16 Os[256][40];   // V-epilogue staging [c][px], pad 40 (16B rows)

  // ---- stage X tile transposed (fp32 -> bf16) ----
  const float* xb = x + (size_t)b * CH * NPIX + n0;
  #pragma unroll
  for (int i = 0; i < 2; ++i) {
    int task = i * 256 + t;
    int ncg  = task & 7;
    int kcg  = task >> 3;
    const float* src = xb + (size_t)(kcg * 4) * NPIX + ncg * 4;
    float rows[4][4];
    *(float4*)&rows[0][0] = *(const float4*)(src);
    *(float4*)&rows[1][0] = *(const float4*)(src + NPIX);
    *(float4*)&rows[2][0] = *(const float4*)(src + 2 * NPIX);
    *(float4*)&rows[3][0] = *(const float4*)(src + 3 * NPIX);
    #pragma unroll
    for (int c = 0; c < 4; ++c) {
      uint2 pk;
      pk.x = pk2(rows[0][c], rows[1][c]);
      pk.y = pk2(rows[2][c], rows[3][c]);
      *(uint2*)&Xs[ncg * 4 + c][kcg * 4] = pk;
    }
  }
  __syncthreads();

  const int w    = t >> 6;
  const int l15  = t & 15;
  const int quad = (t & 63) >> 4;

  floatx4 acc[5][2];
  #pragma unroll
  for (int si = 0; si < 5; ++si)
    #pragma unroll
    for (int nt = 0; nt < 2; ++nt) acc[si][nt] = (floatx4){0.f, 0.f, 0.f, 0.f};

  // W fragments: register double-buffer to hide L2 latency
  short8 afc[5], afn[5];
  #pragma unroll
  for (int si = 0; si < 5; ++si) {
    const int s = w + si * 4;
    afc[si] = *(const short8*)(Wbf + (size_t)(s * 16 + l15) * 256 + quad * 8);
  }
  for (int kc = 0; kc < 8; ++kc) {
    const int k0  = kc * 32;
    const int kn0 = (kc < 7) ? k0 + 32 : 0;
    #pragma unroll
    for (int si = 0; si < 5; ++si) {
      const int s = w + si * 4;
      afn[si] = *(const short8*)(Wbf + (size_t)(s * 16 + l15) * 256 + kn0 + quad * 8);
    }
    short8 bf[2];
    #pragma unroll
    for (int nt = 0; nt < 2; ++nt)
      bf[nt] = *(const short8*)&Xs[l15 + 16 * nt][k0 + quad * 8];
    #pragma unroll
    for (int si = 0; si < 5; ++si)
      #pragma unroll
      for (int nt = 0; nt < 2; ++nt)
        acc[si][nt] = __builtin_amdgcn_mfma_f32_16x16x32_bf16(afc[si], bf[nt], acc[si][nt], 0, 0, 0);
    #pragma unroll
    for (int si = 0; si < 5; ++si) afc[si] = afn[si];
  }

  // ---- epilogue: Q/K direct; V staged in LDS then coalesced uint4 stores ----
  #pragma unroll
  for (int si = 0; si < 5; ++si) {
    const int s = w + si * 4;
    float4 bb = *(const float4*)(Bsw + 16 * s + quad * 4);
    #pragma unroll
    for (int nt = 0; nt < 2; ++nt) {
      const int px  = 16 * nt + l15;
      float v0 = acc[si][nt][0] + bb.x;
      float v1 = acc[si][nt][1] + bb.y;
      float v2 = acc[si][nt][2] + bb.z;
      float v3 = acc[si][nt][3] + bb.w;
      if (s < 4) {
        s16* dst = (s < 2) ? Qw : Kw;
        int d0 = (s & 1) * 16 + quad * 4;
        uint2 pq; pq.x = pk2(v0, v1); pq.y = pk2(v2, v3);
        *(uint2*)(dst + ((size_t)b * NPIX + n0 + px) * DQK + d0) = pq;
      } else {
        const int c0 = (s - 4) * 16 + quad * 4;
        Os[c0 + 0][px] = f2bf(v0);
        Os[c0 + 1][px] = f2bf(v1);
        Os[c0 + 2][px] = f2bf(v2);
        Os[c0 + 3][px] = f2bf(v3);
      }
    }
  }
  __syncthreads();
  #pragma unroll
  for (int rep = 0; rep < 4; ++rep) {
    const int task = rep * 256 + t;        // 1024 tasks = 256 ch x 4 segs
    const int ch   = task >> 2;
    const int seg  = task & 3;
    *(uint4*)(Vw + ((size_t)b * CH + ch) * NPIX + n0 + seg * 8) =
        *(const uint4*)&Os[ch][seg * 8];
  }
}

// ============ attn: 256 blocks (1/CU), 8 waves, full 256 ch per block ======
// block = (b = bi&3 [XCD-locked], qt = bi>>2). 64 queries, all 256 channels.
// S-phase: wave w computes S^T for its 16-key strip (16x16x32, as before),
//   exp -> bf16 -> XOR-swizzled Pt[q][k] (computed ONCE, no h duplication).
// PV-phase: wave w owns channels 32w..32w+31, full 64 q, via 32x32x16 MFMA;
//   each wave reads the 16KB P tile once (4096 b128/CU vs 8192 before).
// Pt swizzle: byte slot' = slot ^ (q&7) -> conflict-free b128 reads by design.
__global__ __launch_bounds__(512, 2) void attn_mfma(
    const s16* __restrict__ Qw, const s16* __restrict__ Kw,
    const s16* __restrict__ Vw, const float* __restrict__ x,
    float* __restrict__ out)
{
  const int bi = blockIdx.x;          // 256 blocks
  const int b  = bi & 3;              // XCD x -> batch x&3 (K/V/Q L2-resident)
  const int qt = bi >> 2;             // 0..63
  const int n0 = qt * 64;
  const int t  = threadIdx.x;
  const int w    = t >> 6;            // wave 0..7
  const int l15  = t & 15;
  const int quad = (t & 63) >> 4;
  const int l31  = t & 31;
  const int lh   = (t & 63) >> 5;     // 0/1
  const int l7   = t & 7;             // == (q & 7) for both write and read rows
  const int cb   = 32 * w;            // wave's 32 output channels

  __shared__ s16  Pt[2][64][128];     // P^T, rows q (256B), swizzled 16B slots
  __shared__ float Lsum[64][8];

  // Q B-frags persistent: B[d=8*quad+j][q=16tq+l15]
  const s16* qbase = Qw + ((size_t)b * NPIX + n0) * DQK;
  short8 qb[4];
  #pragma unroll
  for (int tq = 0; tq < 4; ++tq)
    qb[tq] = *(const short8*)(qbase + (size_t)(16 * tq + l15) * DQK + quad * 8);

  floatx16 o[2];
  #pragma unroll
  for (int i = 0; i < 16; ++i) { o[0][i] = 0.f; o[1][i] = 0.f; }
  float l_part[4] = {0.f, 0.f, 0.f, 0.f};

  const s16* kbase = Kw + (size_t)b * NPIX * DQK;
  const s16* vbase = Vw + ((size_t)b * CH + cb) * NPIX;   // wave's channels

  // prefetch tile 0: K strip + V A-frags (V[ch=cb+l31][k=16ks+8lh..+7])
  short8 ka_c, ka_n, va[8];
  ka_c = *(const short8*)(kbase + (size_t)(16 * w + l15) * DQK + quad * 8);
  #pragma unroll
  for (int ks = 0; ks < 8; ++ks)
    va[ks] = *(const short8*)(vbase + (size_t)l31 * NPIX + 16 * ks + 8 * lh);

  int buf = 0;
  for (int kt = 0; kt < 32; ++kt) {
    const int m0  = kt * 128;
    const int mn0 = (kt < 31) ? m0 + 128 : 0;

    // ---- S^T strip: rows = keys 16w+4quad+r, cols = q = 16tq+l15 ----
    floatx4 sacc[4];
    #pragma unroll
    for (int tq = 0; tq < 4; ++tq)
      sacc[tq] = __builtin_amdgcn_mfma_f32_16x16x32_bf16(
                   ka_c, qb[tq], (floatx4){0.f, 0.f, 0.f, 0.f}, 0, 0, 0);

    ka_n = *(const short8*)(kbase + (size_t)(mn0 + 16 * w + l15) * DQK + quad * 8);

    // ---- p = exp(s), pack bf16, store swizzled: slot = key>>3, ^= (q&7) ----
    const int wslot = (((2 * w + (quad >> 1)) ^ l7) << 3) + (quad & 1) * 4;
    #pragma unroll
    for (int tq = 0; tq < 4; ++tq) {
      float p0 = __expf(fminf(sacc[tq][0], 60.f));
      float p1 = __expf(fminf(sacc[tq][1], 60.f));
      float p2 = __expf(fminf(sacc[tq][2], 60.f));
      float p3 = __expf(fminf(sacc[tq][3], 60.f));
      l_part[tq] += (p0 + p1) + (p2 + p3);
      uint2 pk; pk.x = pk2(p0, p1); pk.y = pk2(p2, p3);
      *(uint2*)&Pt[buf][16 * tq + l15][wslot] = pk;
    }
    __syncthreads();   // Pt[buf] complete (double buffer -> 1 barrier/tile)

    // ---- PV: O[32ch][64q] += V[32ch][128k]·P^T[128k][64q], 32x32x16 ----
    #pragma unroll
    for (int ks = 0; ks < 8; ++ks) {
      const int rslot = ((2 * ks + lh) ^ l7) << 3;
      short8 pb0 = *(const short8*)&Pt[buf][l31     ][rslot];
      short8 pb1 = *(const short8*)&Pt[buf][32 + l31][rslot];
      o[0] = __builtin_amdgcn_mfma_f32_32x32x16_bf16(va[ks], pb0, o[0], 0, 0, 0);
      o[1] = __builtin_amdgcn_mfma_f32_32x32x16_bf16(va[ks], pb1, o[1], 0, 0, 0);
    }
    // refill V for next tile (latency covered by next S/exp/barrier phase)
    #pragma unroll
    for (int ks = 0; ks < 8; ++ks)
      va[ks] = *(const short8*)(vbase + (size_t)l31 * NPIX + mn0 + 16 * ks + 8 * lh);

    ka_c = ka_n;
    buf ^= 1;
  }

  // ---- final l reduction: quads (shfl) then waves (LDS, once) ----
  #pragma unroll
  for (int tq = 0; tq < 4; ++tq) {
    l_part[tq] += __shfl_xor(l_part[tq], 16);
    l_part[tq] += __shfl_xor(l_part[tq], 32);
  }
  if (quad == 0) {
    #pragma unroll
    for (int tq = 0; tq < 4; ++tq) Lsum[16 * tq + l15][w] = l_part[tq];
  }
  __syncthreads();

  // ---- epilogue: normalize + residual. 32x32 C/D: col=q=l31,
  //      row = ch = cb + (r&3) + 8*(r>>2) + 4*lh ----
  #pragma unroll
  for (int half = 0; half < 2; ++half) {
    const int q = half * 32 + l31;
    float4 s0 = *(const float4*)&Lsum[q][0];
    float4 s1 = *(const float4*)&Lsum[q][4];
    float invq = 1.f / (((s0.x + s0.y) + (s0.z + s0.w)) +
                        ((s1.x + s1.y) + (s1.z + s1.w)));
    const int npx = n0 + q;
    #pragma unroll
    for (int r = 0; r < 16; ++r) {
      const int c = cb + (r & 3) + 8 * (r >> 2) + 4 * lh;
      const size_t off = ((size_t)b * CH + c) * NPIX + npx;
      out[off] = fmaf(o[half][r], invq, x[off]);
    }
  }
}

extern "C" void kernel_launch(void* const* d_in, const int* in_sizes, int n_in,
                              void* d_out, int out_size, void* d_ws, size_t ws_size,
                              hipStream_t stream) {
  (void)in_sizes; (void)n_in; (void)out_size; (void)ws_size;
  const float* x  = (const float*)d_in[0];
  const float* Wq = (const float*)d_in[1];
  const float* bq = (const float*)d_in[2];
  const float* Wk = (const float*)d_in[3];
  const float* bk = (const float*)d_in[4];
  const float* Wv = (const float*)d_in[5];
  const float* bv = (const float*)d_in[6];
  float* out = (float*)d_out;

  // ws: Qw 1 MiB @0 | Kw @1 MiB | Vw @2 MiB (8 MiB) | Wbf @10 MiB (160 KiB) |
  //     Bsw @10.25 MiB
  unsigned char* ws = (unsigned char*)d_ws;
  s16*   Qw  = (s16*)ws;
  s16*   Kw  = (s16*)(ws + (size_t)1 * 1024 * 1024);
  s16*   Vw  = (s16*)(ws + (size_t)2 * 1024 * 1024);
  s16*   Wbf = (s16*)(ws + (size_t)10 * 1024 * 1024);
  float* Bsw = (float*)(ws + (size_t)10 * 1024 * 1024 + 256 * 1024);

  hipLaunchKernelGGL(prepack, dim3(80), dim3(256), 0, stream,
                     Wq, bq, Wk, bk, Wv, bv, Wbf, Bsw);
  hipLaunchKernelGGL(proj_mfma, dim3(512), dim3(256), 0, stream,
                     x, Wbf, Bsw, Qw, Kw, Vw);
  hipLaunchKernelGGL(attn_mfma, dim3(256), dim3(512), 0, stream,
                     Qw, Kw, Vw, x, out);
}

// Round 2
// 147.474 us; speedup vs baseline: 1.1269x; 1.0720x over previous
//
#include <hip/hip_runtime.h>
#include <math.h>

#define BATCH 4
#define CH    256
#define NPIX  4096
#define DQK   32

typedef short          s16;
typedef unsigned int   uint_t;
typedef __attribute__((ext_vector_type(8))) short short8;   // 8 bf16 (4 VGPRs)
typedef __attribute__((ext_vector_type(4))) float floatx4;  // MFMA C/D 16x16
typedef __attribute__((ext_vector_type(16))) float floatx16; // MFMA C/D 32x32

__device__ __forceinline__ s16 f2bf(float f) {
  union { float f; uint_t u; } v; v.f = f;
  return (s16)((v.u + 0x8000u) >> 16);
}
__device__ __forceinline__ uint_t pk2(float a, float b) {
  union { float f; uint_t u; } x, y; x.f = a; y.f = b;
  return (((y.u + 0x8000u) >> 16) << 16) | ((x.u + 0x8000u) >> 16);
}

// ============ prepack: W (fp32, rows Q32|K32|V256) -> bf16 [320][256] ======
__global__ __launch_bounds__(256) void prepack(
    const float* __restrict__ Wq, const float* __restrict__ bq,
    const float* __restrict__ Wk, const float* __restrict__ bk,
    const float* __restrict__ Wv, const float* __restrict__ bv,
    s16* __restrict__ Wbf, float* __restrict__ Bsw)
{
  const int gid = blockIdx.x * 256 + threadIdx.x;   // grid 80
  const int e0  = gid * 4;
  const int row = e0 >> 8, col = e0 & 255;
  const float* src = (row < 32) ? Wq + (size_t)row * 256
                   : (row < 64) ? Wk + (size_t)(row - 32) * 256
                                : Wv + (size_t)(row - 64) * 256;
  float4 f = *(const float4*)(src + col);
  uint2 o; o.x = pk2(f.x, f.y); o.y = pk2(f.z, f.w);
  *(uint2*)(Wbf + e0) = o;
  if (gid < 320)
    Bsw[gid] = (gid < 32) ? bq[gid] : (gid < 64) ? bk[gid - 32] : bv[gid - 64];
}

// ============ proj: [Q;K;V] = W'·X, 32-px tiles, grid 512 (2 blocks/CU) ====
// Out: Q,K bf16 [b][n][32] ; V in MFMA-fragment-tiled layout:
//   Vt[((b*8+c)*256+s)*512 + lane*8 + j] = V[c*32+(lane&31)][s*16+8*(lane>>5)+j]
// so attn's A-frag load for (c, k16-block s) is ONE coalesced 1KB b128/wave.
__global__ __launch_bounds__(256, 2) void proj_mfma(
    const float* __restrict__ x, const s16* __restrict__ Wbf,
    const float* __restrict__ Bsw,
    s16* __restrict__ Qw, s16* __restrict__ Kw, s16* __restrict__ Vw)
{
  const int b  = blockIdx.x >> 7;
  const int n0 = (blockIdx.x & 127) << 5;
  const int t  = threadIdx.x;

  __shared__ s16 Xs[32][264];   // [n][k] bf16
  __shared__ s16 Os[256][40];   // V-epilogue staging [c][px], pad 40 (16B rows)

  // ---- stage X tile transposed (fp32 -> bf16) ----
  const float* xb = x + (size_t)b * CH * NPIX + n0;
  #pragma unroll
  for (int i = 0; i < 2; ++i) {
    int task = i * 256 + t;
    int ncg  = task & 7;
    int kcg  = task >> 3;
    const float* src = xb + (size_t)(kcg * 4) * NPIX + ncg * 4;
    float rows[4][4];
    *(float4*)&rows[0][0] = *(const float4*)(src);
    *(float4*)&rows[1][0] = *(const float4*)(src + NPIX);
    *(float4*)&rows[2][0] = *(const float4*)(src + 2 * NPIX);
    *(float4*)&rows[3][0] = *(const float4*)(src + 3 * NPIX);
    #pragma unroll
    for (int c = 0; c < 4; ++c) {
      uint2 pk;
      pk.x = pk2(rows[0][c], rows[1][c]);
      pk.y = pk2(rows[2][c], rows[3][c]);
      *(uint2*)&Xs[ncg * 4 + c][kcg * 4] = pk;
    }
  }
  __syncthreads();

  const int w    = t >> 6;
  const int l15  = t & 15;
  const int quad = (t & 63) >> 4;

  floatx4 acc[5][2];
  #pragma unroll
  for (int si = 0; si < 5; ++si)
    #pragma unroll
    for (int nt = 0; nt < 2; ++nt) acc[si][nt] = (floatx4){0.f, 0.f, 0.f, 0.f};

  // W fragments: register double-buffer to hide L2 latency
  short8 afc[5], afn[5];
  #pragma unroll
  for (int si = 0; si < 5; ++si) {
    const int s = w + si * 4;
    afc[si] = *(const short8*)(Wbf + (size_t)(s * 16 + l15) * 256 + quad * 8);
  }
  for (int kc = 0; kc < 8; ++kc) {
    const int k0  = kc * 32;
    const int kn0 = (kc < 7) ? k0 + 32 : 0;
    #pragma unroll
    for (int si = 0; si < 5; ++si) {
      const int s = w + si * 4;
      afn[si] = *(const short8*)(Wbf + (size_t)(s * 16 + l15) * 256 + kn0 + quad * 8);
    }
    short8 bf[2];
    #pragma unroll
    for (int nt = 0; nt < 2; ++nt)
      bf[nt] = *(const short8*)&Xs[l15 + 16 * nt][k0 + quad * 8];
    #pragma unroll
    for (int si = 0; si < 5; ++si)
      #pragma unroll
      for (int nt = 0; nt < 2; ++nt)
        acc[si][nt] = __builtin_amdgcn_mfma_f32_16x16x32_bf16(afc[si], bf[nt], acc[si][nt], 0, 0, 0);
    #pragma unroll
    for (int si = 0; si < 5; ++si) afc[si] = afn[si];
  }

  // ---- epilogue: Q/K direct; V staged in LDS then tiled-coalesced stores ----
  #pragma unroll
  for (int si = 0; si < 5; ++si) {
    const int s = w + si * 4;
    float4 bb = *(const float4*)(Bsw + 16 * s + quad * 4);
    #pragma unroll
    for (int nt = 0; nt < 2; ++nt) {
      const int px  = 16 * nt + l15;
      float v0 = acc[si][nt][0] + bb.x;
      float v1 = acc[si][nt][1] + bb.y;
      float v2 = acc[si][nt][2] + bb.z;
      float v3 = acc[si][nt][3] + bb.w;
      if (s < 4) {
        s16* dst = (s < 2) ? Qw : Kw;
        int d0 = (s & 1) * 16 + quad * 4;
        uint2 pq; pq.x = pk2(v0, v1); pq.y = pk2(v2, v3);
        *(uint2*)(dst + ((size_t)b * NPIX + n0 + px) * DQK + d0) = pq;
      } else {
        const int c0 = (s - 4) * 16 + quad * 4;
        Os[c0 + 0][px] = f2bf(v0);
        Os[c0 + 1][px] = f2bf(v1);
        Os[c0 + 2][px] = f2bf(v2);
        Os[c0 + 3][px] = f2bf(v3);
      }
    }
  }
  __syncthreads();
  // 1024 tasks = 16 frags (c 0..7 x sl 0..1) x 64 lanes, 16B coalesced stores
  #pragma unroll
  for (int rep = 0; rep < 4; ++rep) {
    const int task = rep * 256 + t;
    const int fid  = task >> 6;
    const int ln   = task & 63;
    const int c    = fid >> 1;
    const int sl   = fid & 1;
    const int row  = c * 32 + (ln & 31);
    const int col  = sl * 16 + (ln >> 5) * 8;
    *(uint4*)(Vw + (((size_t)b * 8 + c) * 256 + (n0 >> 4) + sl) * 512 + ln * 8) =
        *(const uint4*)&Os[row][col];
  }
}

// ============ attn: 256 blocks (1/CU), 16 waves, phase-overlapped ==========
// block = (b = bi&3 [XCD-locked], qt = bi>>2), 64 queries, all 256 channels.
// S roles:  wave w -> key strip sw=w&7 (16 keys), q-half sq=w>>3 (2 MFMA).
// PV roles: wave w -> ch-block c=w>>1 (32 ch), q-half qh=w&1 (8 MFMA 32x32x16).
// 16 waves (4/SIMD): within each barrier window [PV_k | S_{k+1}+exp+write],
// waves naturally stagger -> LDS, VALU, MFMA, L2 pipes overlap.
__global__ __launch_bounds__(1024, 4) void attn_mfma(
    const s16* __restrict__ Qw, const s16* __restrict__ Kw,
    const s16* __restrict__ Vt, const float* __restrict__ x,
    float* __restrict__ out)
{
  const int bi = blockIdx.x;          // 256 blocks
  const int b  = bi & 3;              // XCD x -> batch x&3 (K/V/Q L2-resident)
  const int qt = bi >> 2;             // 0..63
  const int n0 = qt * 64;
  const int t  = threadIdx.x;
  const int w    = t >> 6;            // wave 0..15
  const int lane = t & 63;
  const int l15  = t & 15;
  const int quad = lane >> 4;
  const int l31  = t & 31;
  const int lh   = lane >> 5;
  const int l7   = t & 7;             // == q&7 for both write and read rows
  const int sw   = w & 7;             // S: key strip
  const int sq   = w >> 3;            // S: q half
  const int c    = w >> 1;            // PV: 32-ch block
  const int qh   = w & 1;             // PV: q half

  __shared__ s16  Pt[2][64][128];     // P^T, rows q (256B), swizzled 16B slots
  __shared__ float Lsum[64][8];

  // Q B-frags persistent: B[d=8*quad+j][q = sq*32 + 16tq + l15]
  const s16* qbase = Qw + ((size_t)b * NPIX + n0 + sq * 32) * DQK;
  short8 qb[2];
  #pragma unroll
  for (int tq = 0; tq < 2; ++tq)
    qb[tq] = *(const short8*)(qbase + (size_t)(16 * tq + l15) * DQK + quad * 8);

  floatx16 o;
  #pragma unroll
  for (int i = 0; i < 16; ++i) o[i] = 0.f;
  float l_part[2] = {0.f, 0.f};

  const s16* kbase = Kw + (size_t)b * NPIX * DQK;
  const s16* vtb   = Vt + ((size_t)(b * 8 + c) * 256) * 512 + lane * 8;

  // prefetch tile 0: K strip + V A-frags (coalesced 1KB tiled loads)
  short8 ka_c, ka_n, va[8];
  ka_c = *(const short8*)(kbase + (size_t)(16 * sw + l15) * DQK + quad * 8);
  #pragma unroll
  for (int ks = 0; ks < 8; ++ks)
    va[ks] = *(const short8*)(vtb + (size_t)ks * 512);

  int buf = 0;
  for (int kt = 0; kt < 32; ++kt) {
    const int m0  = kt * 128;
    const int mn0 = (kt < 31) ? m0 + 128 : 0;

    // ---- S^T strip: rows = keys 16sw+4quad+r, cols = q = sq*32+16tq+l15 ----
    floatx4 sacc[2];
    #pragma unroll
    for (int tq = 0; tq < 2; ++tq)
      sacc[tq] = __builtin_amdgcn_mfma_f32_16x16x32_bf16(
                   ka_c, qb[tq], (floatx4){0.f, 0.f, 0.f, 0.f}, 0, 0, 0);

    ka_n = *(const short8*)(kbase + (size_t)(mn0 + 16 * sw + l15) * DQK + quad * 8);

    // ---- p = exp(s), pack bf16, store swizzled: slot = key>>3, ^= (q&7) ----
    const int wslot = (((2 * sw + (quad >> 1)) ^ l7) << 3) + (quad & 1) * 4;
    #pragma unroll
    for (int tq = 0; tq < 2; ++tq) {
      float p0 = __expf(fminf(sacc[tq][0], 60.f));
      float p1 = __expf(fminf(sacc[tq][1], 60.f));
      float p2 = __expf(fminf(sacc[tq][2], 60.f));
      float p3 = __expf(fminf(sacc[tq][3], 60.f));
      l_part[tq] += (p0 + p1) + (p2 + p3);
      uint2 pk; pk.x = pk2(p0, p1); pk.y = pk2(p2, p3);
      *(uint2*)&Pt[buf][sq * 32 + 16 * tq + l15][wslot] = pk;
    }
    __syncthreads();   // Pt[buf] complete (double buffer -> 1 barrier/tile)

    // ---- PV: O[32ch][32q] += V[32ch][128k]·P^T[128k][32q], 32x32x16 ----
    #pragma unroll
    for (int ks = 0; ks < 8; ++ks) {
      const int rslot = ((2 * ks + lh) ^ l7) << 3;
      short8 pb = *(const short8*)&Pt[buf][qh * 32 + l31][rslot];
      o = __builtin_amdgcn_mfma_f32_32x32x16_bf16(va[ks], pb, o, 0, 0, 0);
    }
    // refill V for next tile (latency covered by next S/exp/write phase)
    const int sn = mn0 >> 4;
    #pragma unroll
    for (int ks = 0; ks < 8; ++ks)
      va[ks] = *(const short8*)(vtb + (size_t)(sn + ks) * 512);

    ka_c = ka_n;
    buf ^= 1;
  }

  // ---- final l reduction: quads (shfl) then strips (LDS, once) ----
  #pragma unroll
  for (int tq = 0; tq < 2; ++tq) {
    l_part[tq] += __shfl_xor(l_part[tq], 16);
    l_part[tq] += __shfl_xor(l_part[tq], 32);
  }
  if (quad == 0) {
    #pragma unroll
    for (int tq = 0; tq < 2; ++tq) Lsum[sq * 32 + 16 * tq + l15][sw] = l_part[tq];
  }
  __syncthreads();

  // ---- epilogue: normalize + residual. 32x32 C/D: col=q=l31,
  //      row = ch = c*32 + (r&3) + 8*(r>>2) + 4*lh ----
  {
    const int q = qh * 32 + l31;
    float4 s0 = *(const float4*)&Lsum[q][0];
    float4 s1 = *(const float4*)&Lsum[q][4];
    float invq = 1.f / (((s0.x + s0.y) + (s0.z + s0.w)) +
                        ((s1.x + s1.y) + (s1.z + s1.w)));
    const int npx = n0 + q;
    #pragma unroll
    for (int r = 0; r < 16; ++r) {
      const int ch = c * 32 + (r & 3) + 8 * (r >> 2) + 4 * lh;
      const size_t off = ((size_t)b * CH + ch) * NPIX + npx;
      out[off] = fmaf(o[r], invq, x[off]);
    }
  }
}

extern "C" void kernel_launch(void* const* d_in, const int* in_sizes, int n_in,
                              void* d_out, int out_size, void* d_ws, size_t ws_size,
                              hipStream_t stream) {
  (void)in_sizes; (void)n_in; (void)out_size; (void)ws_size;
  const float* x  = (const float*)d_in[0];
  const float* Wq = (const float*)d_in[1];
  const float* bq = (const float*)d_in[2];
  const float* Wk = (const float*)d_in[3];
  const float* bk = (const float*)d_in[4];
  const float* Wv = (const float*)d_in[5];
  const float* bv = (const float*)d_in[6];
  float* out = (float*)d_out;

  // ws: Qw 1 MiB @0 | Kw @1 MiB | Vt @2 MiB (8 MiB, tiled) | Wbf @10 MiB |
  //     Bsw @10.25 MiB
  unsigned char* ws = (unsigned char*)d_ws;
  s16*   Qw  = (s16*)ws;
  s16*   Kw  = (s16*)(ws + (size_t)1 * 1024 * 1024);
  s16*   Vt  = (s16*)(ws + (size_t)2 * 1024 * 1024);
  s16*   Wbf = (s16*)(ws + (size_t)10 * 1024 * 1024);
  float* Bsw = (float*)(ws + (size_t)10 * 1024 * 1024 + 256 * 1024);

  hipLaunchKernelGGL(prepack, dim3(80), dim3(256), 0, stream,
                     Wq, bq, Wk, bk, Wv, bv, Wbf, Bsw);
  hipLaunchKernelGGL(proj_mfma, dim3(512), dim3(256), 0, stream,
                     x, Wbf, Bsw, Qw, Kw, Vt);
  hipLaunchKernelGGL(attn_mfma, dim3(256), dim3(1024), 0, stream,
                     Qw, Kw, Vt, x, out);
}

// Round 3
// 139.296 us; speedup vs baseline: 1.1931x; 1.0587x over previous
//
#include <hip/hip_runtime.h>
#include <math.h>

#define BATCH 4
#define CH    256
#define NPIX  4096
#define DQK   32

typedef short          s16;
typedef unsigned int   uint_t;
typedef __attribute__((ext_vector_type(8))) short short8;   // 8 bf16 (4 VGPRs)
typedef __attribute__((ext_vector_type(4))) float floatx4;  // MFMA C/D 16x16
typedef __attribute__((ext_vector_type(16))) float floatx16; // MFMA C/D 32x32

__device__ __forceinline__ s16 f2bf(float f) {
  union { float f; uint_t u; } v; v.f = f;
  return (s16)((v.u + 0x8000u) >> 16);
}
__device__ __forceinline__ uint_t pk2(float a, float b) {
  union { float f; uint_t u; } x, y; x.f = a; y.f = b;
  return (((y.u + 0x8000u) >> 16) << 16) | ((x.u + 0x8000u) >> 16);
}

// ============ prepack: W (fp32, rows Q32|K32|V256) -> bf16 [320][256] ======
__global__ __launch_bounds__(256) void prepack(
    const float* __restrict__ Wq, const float* __restrict__ bq,
    const float* __restrict__ Wk, const float* __restrict__ bk,
    const float* __restrict__ Wv, const float* __restrict__ bv,
    s16* __restrict__ Wbf, float* __restrict__ Bsw)
{
  const int gid = blockIdx.x * 256 + threadIdx.x;   // grid 80
  const int e0  = gid * 4;
  const int row = e0 >> 8, col = e0 & 255;
  const float* src = (row < 32) ? Wq + (size_t)row * 256
                   : (row < 64) ? Wk + (size_t)(row - 32) * 256
                                : Wv + (size_t)(row - 64) * 256;
  float4 f = *(const float4*)(src + col);
  uint2 o; o.x = pk2(f.x, f.y); o.y = pk2(f.z, f.w);
  *(uint2*)(Wbf + e0) = o;
  if (gid < 320)
    Bsw[gid] = (gid < 32) ? bq[gid] : (gid < 64) ? bk[gid - 32] : bv[gid - 64];
}

// ============ proj: [Q;K;V] = W'·X, 32-px tiles, grid 512 (2 blocks/CU) ====
// Out: Q,K bf16 [b][n][32] ; V in MFMA-fragment-tiled layout:
//   Vt[((b*8+c)*256+s)*512 + lane*8 + j] = V[c*32+(lane&31)][s*16+8*(lane>>5)+j]
// so attn's A-frag load for (c, k16-block s) is ONE coalesced 1KB b128/wave.
__global__ __launch_bounds__(256, 2) void proj_mfma(
    const float* __restrict__ x, const s16* __restrict__ Wbf,
    const float* __restrict__ Bsw,
    s16* __restrict__ Qw, s16* __restrict__ Kw, s16* __restrict__ Vw)
{
  const int b  = blockIdx.x >> 7;
  const int n0 = (blockIdx.x & 127) << 5;
  const int t  = threadIdx.x;

  __shared__ s16 Xs[32][264];   // [n][k] bf16
  __shared__ s16 Os[256][40];   // V-epilogue staging [c][px], pad 40 (16B rows)

  // ---- stage X tile transposed (fp32 -> bf16) ----
  const float* xb = x + (size_t)b * CH * NPIX + n0;
  #pragma unroll
  for (int i = 0; i < 2; ++i) {
    int task = i * 256 + t;
    int ncg  = task & 7;
    int kcg  = task >> 3;
    const float* src = xb + (size_t)(kcg * 4) * NPIX + ncg * 4;
    float rows[4][4];
    *(float4*)&rows[0][0] = *(const float4*)(src);
    *(float4*)&rows[1][0] = *(const float4*)(src + NPIX);
    *(float4*)&rows[2][0] = *(const float4*)(src + 2 * NPIX);
    *(float4*)&rows[3][0] = *(const float4*)(src + 3 * NPIX);
    #pragma unroll
    for (int c = 0; c < 4; ++c) {
      uint2 pk;
      pk.x = pk2(rows[0][c], rows[1][c]);
      pk.y = pk2(rows[2][c], rows[3][c]);
      *(uint2*)&Xs[ncg * 4 + c][kcg * 4] = pk;
    }
  }
  __syncthreads();

  const int w    = t >> 6;
  const int l15  = t & 15;
  const int quad = (t & 63) >> 4;

  floatx4 acc[5][2];
  #pragma unroll
  for (int si = 0; si < 5; ++si)
    #pragma unroll
    for (int nt = 0; nt < 2; ++nt) acc[si][nt] = (floatx4){0.f, 0.f, 0.f, 0.f};

  // W fragments: register double-buffer to hide L2 latency
  short8 afc[5], afn[5];
  #pragma unroll
  for (int si = 0; si < 5; ++si) {
    const int s = w + si * 4;
    afc[si] = *(const short8*)(Wbf + (size_t)(s * 16 + l15) * 256 + quad * 8);
  }
  for (int kc = 0; kc < 8; ++kc) {
    const int k0  = kc * 32;
    const int kn0 = (kc < 7) ? k0 + 32 : 0;
    #pragma unroll
    for (int si = 0; si < 5; ++si) {
      const int s = w + si * 4;
      afn[si] = *(const short8*)(Wbf + (size_t)(s * 16 + l15) * 256 + kn0 + quad * 8);
    }
    short8 bf[2];
    #pragma unroll
    for (int nt = 0; nt < 2; ++nt)
      bf[nt] = *(const short8*)&Xs[l15 + 16 * nt][k0 + quad * 8];
    #pragma unroll
    for (int si = 0; si < 5; ++si)
      #pragma unroll
      for (int nt = 0; nt < 2; ++nt)
        acc[si][nt] = __builtin_amdgcn_mfma_f32_16x16x32_bf16(afc[si], bf[nt], acc[si][nt], 0, 0, 0);
    #pragma unroll
    for (int si = 0; si < 5; ++si) afc[si] = afn[si];
  }

  // ---- epilogue: Q/K direct; V staged in LDS then tiled-coalesced stores ----
  #pragma unroll
  for (int si = 0; si < 5; ++si) {
    const int s = w + si * 4;
    float4 bb = *(const float4*)(Bsw + 16 * s + quad * 4);
    #pragma unroll
    for (int nt = 0; nt < 2; ++nt) {
      const int px  = 16 * nt + l15;
      float v0 = acc[si][nt][0] + bb.x;
      float v1 = acc[si][nt][1] + bb.y;
      float v2 = acc[si][nt][2] + bb.z;
      float v3 = acc[si][nt][3] + bb.w;
      if (s < 4) {
        s16* dst = (s < 2) ? Qw : Kw;
        int d0 = (s & 1) * 16 + quad * 4;
        uint2 pq; pq.x = pk2(v0, v1); pq.y = pk2(v2, v3);
        *(uint2*)(dst + ((size_t)b * NPIX + n0 + px) * DQK + d0) = pq;
      } else {
        const int c0 = (s - 4) * 16 + quad * 4;
        Os[c0 + 0][px] = f2bf(v0);
        Os[c0 + 1][px] = f2bf(v1);
        Os[c0 + 2][px] = f2bf(v2);
        Os[c0 + 3][px] = f2bf(v3);
      }
    }
  }
  __syncthreads();
  // 1024 tasks = 16 frags (c 0..7 x sl 0..1) x 64 lanes, 16B coalesced stores
  #pragma unroll
  for (int rep = 0; rep < 4; ++rep) {
    const int task = rep * 256 + t;
    const int fid  = task >> 6;
    const int ln   = task & 63;
    const int c    = fid >> 1;
    const int sl   = fid & 1;
    const int row  = c * 32 + (ln & 31);
    const int col  = sl * 16 + (ln >> 5) * 8;
    *(uint4*)(Vw + (((size_t)b * 8 + c) * 256 + (n0 >> 4) + sl) * 512 + ln * 8) =
        *(const uint4*)&Os[row][col];
  }
}

// ============ attn: 256 blocks (1/CU), 16 waves, K-split PV (V read-once) ==
// block = (b = bi&3 [XCD-locked], qt = bi>>2), 64 queries, all 256 channels.
// S roles:  wave w -> key strip sw=w&7 (16 keys), q-half sq=w>>3.
// PV roles: wave w -> ch-block c=w&7 (32 ch), key-half kh=w>>3 (64 of 128 k).
//   Each wave covers ALL 64 q for its (c,kh): V per wave = 4KB/tile ->
//   64KB/tile/CU = the read-once minimum (was 128KB with q-split, 2x dup).
// Partial O over key-halves summed once at the end via Ored (64KB LDS).
__global__ __launch_bounds__(1024, 4) void attn_mfma(
    const s16* __restrict__ Qw, const s16* __restrict__ Kw,
    const s16* __restrict__ Vt, const float* __restrict__ x,
    float* __restrict__ out)
{
  const int bi = blockIdx.x;          // 256 blocks
  const int b  = bi & 3;              // XCD x -> batch x&3 (K/V/Q L2-resident)
  const int qt = bi >> 2;             // 0..63
  const int n0 = qt * 64;
  const int t  = threadIdx.x;
  const int w    = t >> 6;            // wave 0..15
  const int lane = t & 63;
  const int l15  = t & 15;
  const int quad = lane >> 4;
  const int l31  = t & 31;
  const int lh   = lane >> 5;
  const int l7   = t & 7;             // == q&7 for both write and read rows
  const int sw   = w & 7;             // S: key strip
  const int sq   = w >> 3;            // S: q half
  const int c    = w & 7;             // PV: 32-ch block
  const int kh   = w >> 3;            // PV: key half (64 keys of the tile)

  __shared__ s16  Pt[2][64][128];     // P^T, rows q (256B), swizzled 16B slots
  __shared__ float Lsum[64][8];
  __shared__ float Ored[8][32][64];   // kh=1 partial O for cross-kh reduction

  // Q B-frags persistent: B[d=8*quad+j][q = sq*32 + 16tq + l15]
  const s16* qbase = Qw + ((size_t)b * NPIX + n0 + sq * 32) * DQK;
  short8 qb[2];
  #pragma unroll
  for (int tq = 0; tq < 2; ++tq)
    qb[tq] = *(const short8*)(qbase + (size_t)(16 * tq + l15) * DQK + quad * 8);

  floatx16 o[2];                      // o[0]: q 0..31, o[1]: q 32..63
  #pragma unroll
  for (int i = 0; i < 16; ++i) { o[0][i] = 0.f; o[1][i] = 0.f; }
  float l_part[2] = {0.f, 0.f};

  const s16* kbase = Kw + (size_t)b * NPIX * DQK;
  const s16* vtb   = Vt + ((size_t)(b * 8 + c) * 256) * 512 + lane * 8;

  // prefetch tile 0: K strip + V A-frags (coalesced 1KB tiled loads)
  short8 ka_c, ka_n, va[4];
  ka_c = *(const short8*)(kbase + (size_t)(16 * sw + l15) * DQK + quad * 8);
  #pragma unroll
  for (int ks = 0; ks < 4; ++ks)
    va[ks] = *(const short8*)(vtb + (size_t)(ks + 4 * kh) * 512);

  int buf = 0;
  for (int kt = 0; kt < 32; ++kt) {
    const int m0  = kt * 128;
    const int mn0 = (kt < 31) ? m0 + 128 : 0;

    // ---- S^T strip: rows = keys 16sw+4quad+r, cols = q = sq*32+16tq+l15 ----
    floatx4 sacc[2];
    #pragma unroll
    for (int tq = 0; tq < 2; ++tq)
      sacc[tq] = __builtin_amdgcn_mfma_f32_16x16x32_bf16(
                   ka_c, qb[tq], (floatx4){0.f, 0.f, 0.f, 0.f}, 0, 0, 0);

    ka_n = *(const short8*)(kbase + (size_t)(mn0 + 16 * sw + l15) * DQK + quad * 8);

    // ---- p = exp(s), pack bf16, store swizzled: slot = key>>3, ^= (q&7) ----
    const int wslot = (((2 * sw + (quad >> 1)) ^ l7) << 3) + (quad & 1) * 4;
    #pragma unroll
    for (int tq = 0; tq < 2; ++tq) {
      float p0 = __expf(fminf(sacc[tq][0], 60.f));
      float p1 = __expf(fminf(sacc[tq][1], 60.f));
      float p2 = __expf(fminf(sacc[tq][2], 60.f));
      float p3 = __expf(fminf(sacc[tq][3], 60.f));
      l_part[tq] += (p0 + p1) + (p2 + p3);
      uint2 pk; pk.x = pk2(p0, p1); pk.y = pk2(p2, p3);
      *(uint2*)&Pt[buf][sq * 32 + 16 * tq + l15][wslot] = pk;
    }
    __syncthreads();   // Pt[buf] complete (double buffer -> 1 barrier/tile)

    // ---- PV: O[32ch][64q] += V[32ch][64k_half]·P^T[64k_half][64q] ----
    #pragma unroll
    for (int ks = 0; ks < 4; ++ks) {
      const int rslot = ((2 * (ks + 4 * kh) + lh) ^ l7) << 3;
      short8 pb0 = *(const short8*)&Pt[buf][l31     ][rslot];
      short8 pb1 = *(const short8*)&Pt[buf][32 + l31][rslot];
      o[0] = __builtin_amdgcn_mfma_f32_32x32x16_bf16(va[ks], pb0, o[0], 0, 0, 0);
      o[1] = __builtin_amdgcn_mfma_f32_32x32x16_bf16(va[ks], pb1, o[1], 0, 0, 0);
    }
    // refill V for next tile (latency covered by next S/exp/write phase)
    const int sn = mn0 >> 4;
    #pragma unroll
    for (int ks = 0; ks < 4; ++ks)
      va[ks] = *(const short8*)(vtb + (size_t)(sn + ks + 4 * kh) * 512);

    ka_c = ka_n;
    buf ^= 1;
  }

  // ---- final l reduction: quads (shfl) then strips (LDS, once) ----
  #pragma unroll
  for (int tq = 0; tq < 2; ++tq) {
    l_part[tq] += __shfl_xor(l_part[tq], 16);
    l_part[tq] += __shfl_xor(l_part[tq], 32);
  }
  if (quad == 0) {
    #pragma unroll
    for (int tq = 0; tq < 2; ++tq) Lsum[sq * 32 + 16 * tq + l15][sw] = l_part[tq];
  }
  // kh=1 waves stage their partial O for reduction
  if (kh == 1) {
    #pragma unroll
    for (int r = 0; r < 16; ++r) {
      const int chrow = (r & 3) + 8 * (r >> 2) + 4 * lh;
      Ored[c][chrow][l31]      = o[0][r];
      Ored[c][chrow][32 + l31] = o[1][r];
    }
  }
  __syncthreads();

  // ---- epilogue (kh=0 waves): sum key-halves, normalize, residual ----
  if (kh == 0) {
    const int q0 = l31, q1 = 32 + l31;
    float4 a0 = *(const float4*)&Lsum[q0][0];
    float4 a1 = *(const float4*)&Lsum[q0][4];
    float4 b0 = *(const float4*)&Lsum[q1][0];
    float4 b1 = *(const float4*)&Lsum[q1][4];
    float inv0 = 1.f / (((a0.x + a0.y) + (a0.z + a0.w)) +
                        ((a1.x + a1.y) + (a1.z + a1.w)));
    float inv1 = 1.f / (((b0.x + b0.y) + (b0.z + b0.w)) +
                        ((b1.x + b1.y) + (b1.z + b1.w)));
    #pragma unroll
    for (int r = 0; r < 16; ++r) {
      const int chrow = (r & 3) + 8 * (r >> 2) + 4 * lh;
      const int ch = c * 32 + chrow;
      const float s0 = o[0][r] + Ored[c][chrow][l31];
      const float s1 = o[1][r] + Ored[c][chrow][32 + l31];
      const size_t off0 = ((size_t)b * CH + ch) * NPIX + n0 + q0;
      const size_t off1 = ((size_t)b * CH + ch) * NPIX + n0 + q1;
      out[off0] = fmaf(s0, inv0, x[off0]);
      out[off1] = fmaf(s1, inv1, x[off1]);
    }
  }
}

extern "C" void kernel_launch(void* const* d_in, const int* in_sizes, int n_in,
                              void* d_out, int out_size, void* d_ws, size_t ws_size,
                              hipStream_t stream) {
  (void)in_sizes; (void)n_in; (void)out_size; (void)ws_size;
  const float* x  = (const float*)d_in[0];
  const float* Wq = (const float*)d_in[1];
  const float* bq = (const float*)d_in[2];
  const float* Wk = (const float*)d_in[3];
  const float* bk = (const float*)d_in[4];
  const float* Wv = (const float*)d_in[5];
  const float* bv = (const float*)d_in[6];
  float* out = (float*)d_out;

  // ws: Qw 1 MiB @0 | Kw @1 MiB | Vt @2 MiB (8 MiB, tiled) | Wbf @10 MiB |
  //     Bsw @10.25 MiB
  unsigned char* ws = (unsigned char*)d_ws;
  s16*   Qw  = (s16*)ws;
  s16*   Kw  = (s16*)(ws + (size_t)1 * 1024 * 1024);
  s16*   Vt  = (s16*)(ws + (size_t)2 * 1024 * 1024);
  s16*   Wbf = (s16*)(ws + (size_t)10 * 1024 * 1024);
  float* Bsw = (float*)(ws + (size_t)10 * 1024 * 1024 + 256 * 1024);

  hipLaunchKernelGGL(prepack, dim3(80), dim3(256), 0, stream,
                     Wq, bq, Wk, bk, Wv, bv, Wbf, Bsw);
  hipLaunchKernelGGL(proj_mfma, dim3(512), dim3(256), 0, stream,
                     x, Wbf, Bsw, Qw, Kw, Vt);
  hipLaunchKernelGGL(attn_mfma, dim3(256), dim3(1024), 0, stream,
                     Qw, Kw, Vt, x, out);
}